// Round 1
// baseline (7052.486 us; speedup 1.0000x reference)
//
#include <hip/hip_runtime.h>
#include <cstdint>
#include <cstddef>

typedef __bf16 bf8 __attribute__((ext_vector_type(8)));
typedef float  f4  __attribute__((ext_vector_type(4)));
typedef float  f2  __attribute__((ext_vector_type(2)));

#define OUT0 0ull          // outputs (B,T,1026)
#define OUT1 67239936ull   // zf (1,B,1026)
#define OUT2 67502592ull   // czf (1,B,1026)
#define OUT3 67765248ull   // coefficients (B,T,2)
#define OUT4 67896320ull   // mats (T,2,2)

__device__ __forceinline__ float sigm(float x) {
  float e = __expf(-fabsf(x));
  float r = 1.f / (1.f + e);
  return x >= 0.f ? r : 1.f - r;
}
__device__ __forceinline__ float tanh_f(float x) {
  float e = __expf(-2.f * fabsf(x));
  float r = (1.f - e) / (1.f + e);
  return x >= 0.f ? r : -r;
}

__global__ void ws_init(uint32_t* ws) { ws[threadIdx.x] = 0u; }

// Per-M-group barrier: monotonic arrival counter, no reset (ws re-poisoned each call,
// zeroed by ws_init). 32 blocks per group.
__device__ __forceinline__ void mbar(uint32_t* __restrict__ bar, int Mg, uint32_t target, int tid) {
  __syncthreads();  // all waves drained (compiler emits s_waitcnt vmcnt(0) before s_barrier)
  if (tid == 0) {
    __hip_atomic_fetch_add(bar + Mg * 32, 1u, __ATOMIC_ACQ_REL, __HIP_MEMORY_SCOPE_AGENT);
    while (__hip_atomic_load(bar + Mg * 32, __ATOMIC_ACQUIRE, __HIP_MEMORY_SCOPE_AGENT) < target)
      __builtin_amdgcn_s_sleep(2);
  }
  __syncthreads();
  __builtin_amdgcn_fence(__ATOMIC_ACQUIRE, "agent");  // invalidate stale L1/L2 h lines
}

__launch_bounds__(256, 1)
__global__ void lstm_persist(
    const float* __restrict__ inp,  // (256,256,2)
    const float* __restrict__ tau,  // (256,256,1)
    const float* __restrict__ z0,   // (1,256,1026)
    const float* __restrict__ cz0,  // (1,256,1026)
    const float* __restrict__ Wu,   // (4096,1028)
    const float* __restrict__ Wub,  // (4096)
    const float* __restrict__ aw,   // (2,1024)
    const float* __restrict__ ab,   // (2)
    const float* __restrict__ wxw,  // (2,1024)
    const float* __restrict__ wxb,  // (2)
    float* __restrict__ out,
    uint32_t* __restrict__ bar,
    __bf16* __restrict__ hbuf)      // 2 x 256 x 1024 bf16 ping-pong
{
  // LDS: split-K partials, transposed [col][m] at f4 granularity, stride 9 f4 (pad 36 words)
  __shared__ f4    red4[4 * 80 * 9];   // 46080 B (2-round: 80 cols per round)
  __shared__ float chead[144 * 5];     // W[:,0:4] + bias per local col
  __shared__ float cab[4];             // ab0, ab1, wxb0, wxb1
  __shared__ float xsh[64];            // x^255 publish for final pass

  const int tid = threadIdx.x;
  const int bid = blockIdx.x;
  const int Mg  = bid & 7;     // batch group: rows [Mg*32, Mg*32+32)
  const int hb  = bid >> 3;    // h-dim block: dims [hb*32, hb*32+32)
  const int h0  = hb * 32;
  const int w   = tid >> 6;    // wave id: K-slice [w*256, w*256+256)
  const int l   = tid & 63;
  const int cl  = l & 15;      // MFMA 16-dim lane index
  const int q   = l >> 4;      // MFMA quad

  // ---- stage per-column head coefficients (x,inp weights + bias) ----
  if (tid < 144) {
    int c = tid;
    if (c < 128) {
      int rw = (c >> 5) * 1024 + h0 + (c & 31);
      size_t ro = (size_t)rw * 1028;
      chead[c*5+0] = Wu[ro+0]; chead[c*5+1] = Wu[ro+1];
      chead[c*5+2] = Wu[ro+2]; chead[c*5+3] = Wu[ro+3];
      chead[c*5+4] = Wub[rw];
    } else {
      chead[c*5+0] = 0.f; chead[c*5+1] = 0.f; chead[c*5+2] = 0.f;
      chead[c*5+3] = 0.f; chead[c*5+4] = 0.f;
    }
  }
  if (tid == 200) { cab[0] = ab[0]; cab[1] = ab[1]; cab[2] = wxb[0]; cab[3] = wxb[1]; }

  // ---- load stationary B fragments into registers (fp32 -> bf16 RNE) ----
  // B[k][n] = W_row(n)[k];  lane holds n = n0 + cl, k = k0 + q*8 + j
  bf8 bfr[9][8];
  {
    #pragma unroll
    for (int nt = 0; nt < 9; ++nt) {
      const int c = nt * 16 + cl;
      const float* src; bool valid = true;
      if (c < 128)      src = Wu  + (size_t)((c >> 5) * 1024 + h0 + (c & 31)) * 1028 + 4;
      else if (c < 130) src = aw  + (size_t)(c - 128) * 1024;
      else if (c < 132) src = wxw + (size_t)(c - 130) * 1024;
      else { valid = false; src = Wu; }
      #pragma unroll
      for (int ks = 0; ks < 8; ++ks) {
        const int k = w * 256 + ks * 32 + q * 8;
        bf8 bv;
        #pragma unroll
        for (int j = 0; j < 8; ++j) bv[j] = valid ? (__bf16)src[k + j] : (__bf16)0.f;
        bfr[nt][ks] = bv;
      }
    }
  }

  // ---- epilogue lane mapping: lane = (m-quad mq, dim jl) ----
  const int mq   = l & 7;            // rows m = 4*mq .. 4*mq+3 (local)
  const int jl   = w * 8 + (l >> 3); // local dim 0..31
  const int gd   = h0 + jl;          // global h dim
  const int row0 = Mg * 32 + mq * 4; // global batch row base

  float cst[4], x1[4], x2[4], up0[4];
  #pragma unroll
  for (int r = 0; r < 4; ++r) {
    const int row = row0 + r;
    cst[r] = cz0[(size_t)row * 1026 + 2 + gd];
    x1[r]  = z0[(size_t)row * 1026 + 0];
    x2[r]  = z0[(size_t)row * 1026 + 1];
    up0[r] = 0.f;
    // stage h^0 into ping buffer (device-visible sc1 store)
    __bf16 hbv = (__bf16)z0[(size_t)row * 1026 + 2 + gd];
    __hip_atomic_store((unsigned short*)(hbuf + (size_t)row * 1024 + gd),
                       __builtin_bit_cast(unsigned short, hbv),
                       __ATOMIC_RELAXED, __HIP_MEMORY_SCOPE_AGENT);
  }
  // czf x-part (c_x is carried unchanged)
  if (hb == 0 && w == 0 && (l >> 3) == 0) {
    #pragma unroll
    for (int r = 0; r < 4; ++r) {
      const int row = row0 + r;
      f2 cx = *(const f2*)(cz0 + (size_t)row * 1026);
      __builtin_nontemporal_store(cx, (f2*)(out + OUT2 + (size_t)row * 1026));
    }
  }

  // A-fragment address (lane part): row = Mg*32 + mt*16 + cl, k = w*256 + ks*32 + q*8
  const size_t aoff = (size_t)(Mg * 32 + cl) * 1024 + (size_t)(w * 256 + q * 8);

  mbar(bar, Mg, 32u, tid);  // epoch 1: h^0 staged everywhere

  #pragma unroll 1
  for (int t = 0; t < 256; ++t) {
    const __bf16* hr = hbuf + (size_t)(t & 1) * (256 * 1024);
    __bf16*       hw = hbuf + (size_t)((t + 1) & 1) * (256 * 1024);

    // prefetch per-row scalars (inp_t, tau_{t-1})
    f2 uvr[4]; float tpr[4];
    #pragma unroll
    for (int r = 0; r < 4; ++r) {
      const int row = row0 + r;
      uvr[r] = *(const f2*)(inp + (size_t)row * 512 + t * 2);
      tpr[r] = t ? tau[(size_t)row * 256 + (t - 1)] : 0.f;
    }

    // ---- phase 1: MFMA over K (h part) + alpha/Wx extra columns ----
    f4 acc[2][9];
    #pragma unroll
    for (int mt = 0; mt < 2; ++mt)
      #pragma unroll
      for (int nt = 0; nt < 9; ++nt) {
        f4 zz = {0.f, 0.f, 0.f, 0.f};
        acc[mt][nt] = zz;
      }

    bf8 afr[2][4];
    #pragma unroll
    for (int p = 0; p < 4; ++p) {
      afr[0][p] = *(const bf8*)(hr + aoff + p * 32);
      afr[1][p] = *(const bf8*)(hr + aoff + 16 * 1024 + p * 32);
    }
    #pragma unroll
    for (int ks = 0; ks < 8; ++ks) {
      bf8 a0 = afr[0][ks & 3], a1 = afr[1][ks & 3];
      if (ks < 4) {
        afr[0][ks & 3] = *(const bf8*)(hr + aoff + (ks + 4) * 32);
        afr[1][ks & 3] = *(const bf8*)(hr + aoff + 16 * 1024 + (ks + 4) * 32);
      }
      #pragma unroll
      for (int nt = 0; nt < 9; ++nt) {
        acc[0][nt] = __builtin_amdgcn_mfma_f32_16x16x32_bf16(a0, bfr[nt][ks], acc[0][nt], 0, 0, 0);
        acc[1][nt] = __builtin_amdgcn_mfma_f32_16x16x32_bf16(a1, bfr[nt][ks], acc[1][nt], 0, 0, 0);
      }
    }

    // ---- phase 2/3 round 0: gates i,f (cols 0..63) ----
    #pragma unroll
    for (int nt = 0; nt < 4; ++nt) {
      const int cc = nt * 16 + cl;
      red4[(w * 80 + cc) * 9 + q]     = acc[0][nt];
      red4[(w * 80 + cc) * 9 + 4 + q] = acc[1][nt];
    }
    __syncthreads();
    f4 gva[2];
    #pragma unroll
    for (int g = 0; g < 2; ++g) {
      f4 s = {0.f, 0.f, 0.f, 0.f};
      #pragma unroll
      for (int wp = 0; wp < 4; ++wp) s += red4[(wp * 80 + g * 32 + jl) * 9 + mq];
      gva[g] = s;
    }
    __syncthreads();
    // ---- round 1: gates g,o + alpha/Wx extras (cols 64..143 -> cc 0..79) ----
    #pragma unroll
    for (int nt = 4; nt < 9; ++nt) {
      const int cc = nt * 16 + cl - 64;
      red4[(w * 80 + cc) * 9 + q]     = acc[0][nt];
      red4[(w * 80 + cc) * 9 + 4 + q] = acc[1][nt];
    }
    __syncthreads();
    f4 gvb[2], alv[2], wxv[2];
    #pragma unroll
    for (int g = 0; g < 2; ++g) {
      f4 s = {0.f, 0.f, 0.f, 0.f};
      #pragma unroll
      for (int wp = 0; wp < 4; ++wp) s += red4[(wp * 80 + g * 32 + jl) * 9 + mq];
      gvb[g] = s;
    }
    #pragma unroll
    for (int s2 = 0; s2 < 2; ++s2) {
      f4 sa = {0.f, 0.f, 0.f, 0.f}, sw = {0.f, 0.f, 0.f, 0.f};
      #pragma unroll
      for (int wp = 0; wp < 4; ++wp) {
        sa += red4[(wp * 80 + 64 + s2) * 9 + mq];
        sw += red4[(wp * 80 + 66 + s2) * 9 + mq];
      }
      alv[s2] = sa; wxv[s2] = sw;
    }

    // ---- deferred x-update: alpha_{t-1} from h^t, x^t; write outputs[t-1].x ----
    if (t > 0) {
      const float ab0 = cab[0], ab1 = cab[1], wb0 = cab[2], wb1 = cab[3];
      #pragma unroll
      for (int r = 0; r < 4; ++r) {
        const float aa0 = sigm(alv[0][r] + ab0), aa1 = sigm(alv[1][r] + ab1);
        const float X1 = x1[r], X2 = x2[r];
        const float dx1 = X2;
        const float dx2 = (-1.f - 2.f * X1 * X2) * X1 + (1.f - X1 * X1) * X2 + up0[r];
        const float xm1 = X1 + tpr[r] * dx1, xm2 = X2 + tpr[r] * dx2;
        const float xn1 = (1.f - aa0) * xm1 + aa0 * (wxv[0][r] + wb0);
        const float xn2 = (1.f - aa1) * xm2 + aa1 * (wxv[1][r] + wb1);
        x1[r] = xn1; x2[r] = xn2;
        if (hb == 0 && w == 0 && (l >> 3) == 0) {
          const int row = row0 + r;
          f2 xv = {xn1, xn2};
          f2 av = {aa0, aa1};
          __builtin_nontemporal_store(xv, (f2*)(out + OUT0 + (size_t)row * 262656 + (size_t)(t - 1) * 1026));
          __builtin_nontemporal_store(av, (f2*)(out + OUT3 + (size_t)row * 512 + (t - 1) * 2));
        }
      }
    }
    if (bid == 0 && tid == 0) {  // mats[t] from x^t (batch row 0)
      f4 mv = {0.f, 1.f, -1.f - 2.f * x1[0] * x2[0], 1.f - x1[0] * x1[0]};
      __builtin_nontemporal_store(mv, (f4*)(out + OUT4 + (size_t)t * 4));
    }

    // ---- gates: add x/inp head + bias, nonlinearities, c/h update ----
    float hcoef[4][5];
    #pragma unroll
    for (int g = 0; g < 4; ++g) {
      const int c5 = (g * 32 + jl) * 5;
      #pragma unroll
      for (int z = 0; z < 5; ++z) hcoef[g][z] = chead[c5 + z];
    }
    #pragma unroll
    for (int r = 0; r < 4; ++r) {
      float gvals[4] = {gva[0][r], gva[1][r], gvb[0][r], gvb[1][r]};
      #pragma unroll
      for (int g = 0; g < 4; ++g)
        gvals[g] += x1[r] * hcoef[g][0] + x2[r] * hcoef[g][1]
                  + uvr[r][0] * hcoef[g][2] + uvr[r][1] * hcoef[g][3] + hcoef[g][4];
      const float iv = sigm(gvals[0]), fv = sigm(gvals[1]);
      const float gg = tanh_f(gvals[2]), ov = sigm(gvals[3]);
      const float cn = fv * cst[r] + iv * gg;
      const float hn = ov * tanh_f(cn);
      cst[r] = cn;
      const int row = row0 + r;
      __bf16 hbv = (__bf16)hn;
      __hip_atomic_store((unsigned short*)(hw + (size_t)row * 1024 + gd),
                         __builtin_bit_cast(unsigned short, hbv),
                         __ATOMIC_RELAXED, __HIP_MEMORY_SCOPE_AGENT);
      __builtin_nontemporal_store(hn, out + OUT0 + (size_t)row * 262656 + (size_t)t * 1026 + 2 + gd);
      if (t == 255) {
        __builtin_nontemporal_store(hn, out + OUT1 + (size_t)row * 1026 + 2 + gd);
        __builtin_nontemporal_store(cn, out + OUT2 + (size_t)row * 1026 + 2 + gd);
      }
      up0[r] = uvr[r][0];
    }
    if (t == 255 && w == 0 && (l >> 3) == 0) {  // publish x^255 for final pass
      #pragma unroll
      for (int r = 0; r < 4; ++r) {
        xsh[(mq * 4 + r) * 2 + 0] = x1[r];
        xsh[(mq * 4 + r) * 2 + 1] = x2[r];
      }
    }

    mbar(bar, Mg, 32u * (uint32_t)(t + 2), tid);
  }

  // ---- final pass: alpha_255 / x^256 from h^256 (VALU dots; hb==0 blocks only) ----
  if (hb == 0 && tid < 32) {
    const int m = tid, row = Mg * 32 + m;
    const __bf16* hp = hbuf + (size_t)row * 1024;  // h^256 lives in buf0
    float s0 = 0.f, s1 = 0.f, s2 = 0.f, s3 = 0.f;
    #pragma unroll 2
    for (int k = 0; k < 1024; k += 8) {
      bf8 hv = *(const bf8*)(hp + k);
      #pragma unroll
      for (int j = 0; j < 8; ++j) {
        const float hf = (float)hv[j];
        s0 += hf * aw[k + j];        s1 += hf * aw[1024 + k + j];
        s2 += hf * wxw[k + j];       s3 += hf * wxw[1024 + k + j];
      }
    }
    const float aa0 = sigm(s0 + cab[0]), aa1 = sigm(s1 + cab[1]);
    const float X1 = xsh[m * 2], X2 = xsh[m * 2 + 1];
    const float u0 = inp[(size_t)row * 512 + 510];
    const float tp = tau[(size_t)row * 256 + 255];
    const float dx1 = X2;
    const float dx2 = (-1.f - 2.f * X1 * X2) * X1 + (1.f - X1 * X1) * X2 + u0;
    const float xm1 = X1 + tp * dx1, xm2 = X2 + tp * dx2;
    const float xn1 = (1.f - aa0) * xm1 + aa0 * (s2 + cab[2]);
    const float xn2 = (1.f - aa1) * xm2 + aa1 * (s3 + cab[3]);
    f2 xv = {xn1, xn2};
    f2 av = {aa0, aa1};
    __builtin_nontemporal_store(xv, (f2*)(out + OUT0 + (size_t)row * 262656 + (size_t)255 * 1026));
    __builtin_nontemporal_store(av, (f2*)(out + OUT3 + (size_t)row * 512 + 510));
    __builtin_nontemporal_store(xv, (f2*)(out + OUT1 + (size_t)row * 1026));
  }
}

extern "C" void kernel_launch(void* const* d_in, const int* in_sizes, int n_in,
                              void* d_out, int out_size, void* d_ws, size_t ws_size,
                              hipStream_t stream) {
  (void)in_sizes; (void)n_in; (void)out_size; (void)ws_size;
  uint32_t* bar = (uint32_t*)d_ws;
  __bf16* hbuf = (__bf16*)((char*)d_ws + 4096);  // 2 x 256 x 1024 bf16 = 1 MB

  ws_init<<<dim3(1), dim3(256), 0, stream>>>(bar);
  lstm_persist<<<dim3(256), dim3(256), 0, stream>>>(
      (const float*)d_in[0], (const float*)d_in[1], (const float*)d_in[2],
      (const float*)d_in[3], (const float*)d_in[4], (const float*)d_in[5],
      (const float*)d_in[6], (const float*)d_in[7], (const float*)d_in[8],
      (const float*)d_in[9], (float*)d_out, bar, hbuf);
}

// Round 2
// 2785.076 us; speedup vs baseline: 2.5322x; 2.5322x over previous
//
#include <hip/hip_runtime.h>
#include <cstdint>
#include <cstddef>

typedef __bf16 bf8 __attribute__((ext_vector_type(8)));
typedef float  f4  __attribute__((ext_vector_type(4)));
typedef float  f2  __attribute__((ext_vector_type(2)));
typedef unsigned long long u64;

#define OUT0 0ull          // outputs (B,T,1026)
#define OUT1 67239936ull   // zf (1,B,1026)
#define OUT2 67502592ull   // czf (1,B,1026)
#define OUT3 67765248ull   // coefficients (B,T,2)
#define OUT4 67896320ull   // mats (T,2,2)

__device__ __forceinline__ float sigm(float x) {
  float e = __expf(-fabsf(x));
  float r = 1.f / (1.f + e);
  return x >= 0.f ? r : 1.f - r;
}
__device__ __forceinline__ float tanh_f(float x) {
  float e = __expf(-2.f * fabsf(x));
  float r = (1.f - e) / (1.f + e);
  return x >= 0.f ? r : -r;
}

// Coherence-point (sc1) 16B load of 8 bf16, as two relaxed agent-scope 8B atomic
// loads -> global_load_dwordx2 ... sc1, NO buffer_inv, compiler-managed vmcnt.
__device__ __forceinline__ bf8 ld_h(const __bf16* p) {
  u64 a = __hip_atomic_load((u64*)(void*)p,       __ATOMIC_RELAXED, __HIP_MEMORY_SCOPE_AGENT);
  u64 b = __hip_atomic_load((u64*)(void*)p + 1,   __ATOMIC_RELAXED, __HIP_MEMORY_SCOPE_AGENT);
  union { u64 q[2]; bf8 v; } u; u.q[0] = a; u.q[1] = b;
  return u.v;
}

__global__ void ws_init(uint32_t* ws) { ws[threadIdx.x] = 0u; }

// Per-M-group barrier: monotonic arrival counter, ALL-RELAXED (no buffer_inv /
// buffer_wbl2). Visibility argument: every cross-block datum (h, counter) moves
// with sc1 accesses that hit the device coherence point (MALL); __syncthreads
// drains each wave's vmcnt so sc1 h-stores are globally visible before tid0's
// counter increment; consumer sc1 loads bypass L1/L2 so they can't read stale.
__device__ __forceinline__ void mbar(uint32_t* __restrict__ bar, int Mg, uint32_t target, int tid) {
  __syncthreads();  // drains vmcnt(0) per wave: h sc1-stores are at the MALL
  if (tid == 0) {
    __hip_atomic_fetch_add(bar + Mg * 32, 1u, __ATOMIC_RELAXED, __HIP_MEMORY_SCOPE_AGENT);
    while (__hip_atomic_load(bar + Mg * 32, __ATOMIC_RELAXED, __HIP_MEMORY_SCOPE_AGENT) < target)
      __builtin_amdgcn_s_sleep(1);
  }
  __syncthreads();
}

__launch_bounds__(256, 1)
__global__ void lstm_persist(
    const float* __restrict__ inp,  // (256,256,2)
    const float* __restrict__ tau,  // (256,256,1)
    const float* __restrict__ z0,   // (1,256,1026)
    const float* __restrict__ cz0,  // (1,256,1026)
    const float* __restrict__ Wu,   // (4096,1028)
    const float* __restrict__ Wub,  // (4096)
    const float* __restrict__ aw,   // (2,1024)
    const float* __restrict__ ab,   // (2)
    const float* __restrict__ wxw,  // (2,1024)
    const float* __restrict__ wxb,  // (2)
    float* __restrict__ out,
    uint32_t* __restrict__ bar,
    __bf16* __restrict__ hbuf)      // 2 x 256 x 1024 bf16 ping-pong
{
  // LDS: split-K partials, transposed [col][m] at f4 granularity, stride 9 f4 (pad 36 words)
  __shared__ f4    red4[4 * 80 * 9];   // 46080 B (2-round: 80 cols per round)
  __shared__ float chead[144 * 5];     // W[:,0:4] + bias per local col
  __shared__ float cab[4];             // ab0, ab1, wxb0, wxb1
  __shared__ float xsh[64];            // x^255 publish for final pass

  const int tid = threadIdx.x;
  const int bid = blockIdx.x;
  const int Mg  = bid & 7;     // batch group: rows [Mg*32, Mg*32+32)
  const int hb  = bid >> 3;    // h-dim block: dims [hb*32, hb*32+32)
  const int h0  = hb * 32;
  const int w   = tid >> 6;    // wave id: K-slice [w*256, w*256+256)
  const int l   = tid & 63;
  const int cl  = l & 15;      // MFMA 16-dim lane index
  const int q   = l >> 4;      // MFMA quad

  // ---- stage per-column head coefficients (x,inp weights + bias) ----
  if (tid < 144) {
    int c = tid;
    if (c < 128) {
      int rw = (c >> 5) * 1024 + h0 + (c & 31);
      size_t ro = (size_t)rw * 1028;
      chead[c*5+0] = Wu[ro+0]; chead[c*5+1] = Wu[ro+1];
      chead[c*5+2] = Wu[ro+2]; chead[c*5+3] = Wu[ro+3];
      chead[c*5+4] = Wub[rw];
    } else {
      chead[c*5+0] = 0.f; chead[c*5+1] = 0.f; chead[c*5+2] = 0.f;
      chead[c*5+3] = 0.f; chead[c*5+4] = 0.f;
    }
  }
  if (tid == 200) { cab[0] = ab[0]; cab[1] = ab[1]; cab[2] = wxb[0]; cab[3] = wxb[1]; }

  // ---- load stationary B fragments into registers (fp32 -> bf16 RNE) ----
  // B[k][n] = W_row(n)[k];  lane holds n = n0 + cl, k = k0 + q*8 + j
  bf8 bfr[9][8];
  {
    #pragma unroll
    for (int nt = 0; nt < 9; ++nt) {
      const int c = nt * 16 + cl;
      const float* src; bool valid = true;
      if (c < 128)      src = Wu  + (size_t)((c >> 5) * 1024 + h0 + (c & 31)) * 1028 + 4;
      else if (c < 130) src = aw  + (size_t)(c - 128) * 1024;
      else if (c < 132) src = wxw + (size_t)(c - 130) * 1024;
      else { valid = false; src = Wu; }
      #pragma unroll
      for (int ks = 0; ks < 8; ++ks) {
        const int k = w * 256 + ks * 32 + q * 8;
        bf8 bv;
        #pragma unroll
        for (int j = 0; j < 8; ++j) bv[j] = valid ? (__bf16)src[k + j] : (__bf16)0.f;
        bfr[nt][ks] = bv;
      }
    }
  }

  // ---- epilogue lane mapping: lane = (m-quad mq, dim jl) ----
  const int mq   = l & 7;            // rows m = 4*mq .. 4*mq+3 (local)
  const int jl   = w * 8 + (l >> 3); // local dim 0..31
  const int gd   = h0 + jl;          // global h dim
  const int row0 = Mg * 32 + mq * 4; // global batch row base

  float cst[4], x1[4], x2[4], up0[4];
  #pragma unroll
  for (int r = 0; r < 4; ++r) {
    const int row = row0 + r;
    cst[r] = cz0[(size_t)row * 1026 + 2 + gd];
    x1[r]  = z0[(size_t)row * 1026 + 0];
    x2[r]  = z0[(size_t)row * 1026 + 1];
    up0[r] = 0.f;
    // stage h^0 into ping buffer (sc1 write-through store)
    __bf16 hbv = (__bf16)z0[(size_t)row * 1026 + 2 + gd];
    __hip_atomic_store((unsigned short*)(hbuf + (size_t)row * 1024 + gd),
                       __builtin_bit_cast(unsigned short, hbv),
                       __ATOMIC_RELAXED, __HIP_MEMORY_SCOPE_AGENT);
  }
  // czf x-part (c_x is carried unchanged)
  if (hb == 0 && w == 0 && (l >> 3) == 0) {
    #pragma unroll
    for (int r = 0; r < 4; ++r) {
      const int row = row0 + r;
      f2 cx = *(const f2*)(cz0 + (size_t)row * 1026);
      __builtin_nontemporal_store(cx, (f2*)(out + OUT2 + (size_t)row * 1026));
    }
  }

  // A-fragment address (lane part): row = Mg*32 + mt*16 + cl, k = w*256 + ks*32 + q*8
  const size_t aoff = (size_t)(Mg * 32 + cl) * 1024 + (size_t)(w * 256 + q * 8);

  mbar(bar, Mg, 32u, tid);  // epoch 1: h^0 staged everywhere

  #pragma unroll 1
  for (int t = 0; t < 256; ++t) {
    const __bf16* hr = hbuf + (size_t)(t & 1) * (256 * 1024);
    __bf16*       hw = hbuf + (size_t)((t + 1) & 1) * (256 * 1024);

    // prefetch per-row scalars (inp_t, tau_{t-1})
    f2 uvr[4]; float tpr[4];
    #pragma unroll
    for (int r = 0; r < 4; ++r) {
      const int row = row0 + r;
      uvr[r] = *(const f2*)(inp + (size_t)row * 512 + t * 2);
      tpr[r] = t ? tau[(size_t)row * 256 + (t - 1)] : 0.f;
    }

    // ---- phase 1: MFMA over K (h part) + alpha/Wx extra columns ----
    f4 acc[2][9];
    #pragma unroll
    for (int mt = 0; mt < 2; ++mt)
      #pragma unroll
      for (int nt = 0; nt < 9; ++nt) {
        f4 zz = {0.f, 0.f, 0.f, 0.f};
        acc[mt][nt] = zz;
      }

    bf8 afr[2][4];
    #pragma unroll
    for (int p = 0; p < 4; ++p) {
      afr[0][p] = ld_h(hr + aoff + p * 32);
      afr[1][p] = ld_h(hr + aoff + 16 * 1024 + p * 32);
    }
    #pragma unroll
    for (int ks = 0; ks < 8; ++ks) {
      bf8 a0 = afr[0][ks & 3], a1 = afr[1][ks & 3];
      if (ks < 4) {
        afr[0][ks & 3] = ld_h(hr + aoff + (ks + 4) * 32);
        afr[1][ks & 3] = ld_h(hr + aoff + 16 * 1024 + (ks + 4) * 32);
      }
      #pragma unroll
      for (int nt = 0; nt < 9; ++nt) {
        acc[0][nt] = __builtin_amdgcn_mfma_f32_16x16x32_bf16(a0, bfr[nt][ks], acc[0][nt], 0, 0, 0);
        acc[1][nt] = __builtin_amdgcn_mfma_f32_16x16x32_bf16(a1, bfr[nt][ks], acc[1][nt], 0, 0, 0);
      }
    }

    // ---- phase 2/3 round 0: gates i,f (cols 0..63) ----
    #pragma unroll
    for (int nt = 0; nt < 4; ++nt) {
      const int cc = nt * 16 + cl;
      red4[(w * 80 + cc) * 9 + q]     = acc[0][nt];
      red4[(w * 80 + cc) * 9 + 4 + q] = acc[1][nt];
    }
    __syncthreads();
    f4 gva[2];
    #pragma unroll
    for (int g = 0; g < 2; ++g) {
      f4 s = {0.f, 0.f, 0.f, 0.f};
      #pragma unroll
      for (int wp = 0; wp < 4; ++wp) s += red4[(wp * 80 + g * 32 + jl) * 9 + mq];
      gva[g] = s;
    }
    __syncthreads();
    // ---- round 1: gates g,o + alpha/Wx extras (cols 64..143 -> cc 0..79) ----
    #pragma unroll
    for (int nt = 4; nt < 9; ++nt) {
      const int cc = nt * 16 + cl - 64;
      red4[(w * 80 + cc) * 9 + q]     = acc[0][nt];
      red4[(w * 80 + cc) * 9 + 4 + q] = acc[1][nt];
    }
    __syncthreads();
    f4 gvb[2], alv[2], wxv[2];
    #pragma unroll
    for (int g = 0; g < 2; ++g) {
      f4 s = {0.f, 0.f, 0.f, 0.f};
      #pragma unroll
      for (int wp = 0; wp < 4; ++wp) s += red4[(wp * 80 + g * 32 + jl) * 9 + mq];
      gvb[g] = s;
    }
    #pragma unroll
    for (int s2 = 0; s2 < 2; ++s2) {
      f4 sa = {0.f, 0.f, 0.f, 0.f}, sw = {0.f, 0.f, 0.f, 0.f};
      #pragma unroll
      for (int wp = 0; wp < 4; ++wp) {
        sa += red4[(wp * 80 + 64 + s2) * 9 + mq];
        sw += red4[(wp * 80 + 66 + s2) * 9 + mq];
      }
      alv[s2] = sa; wxv[s2] = sw;
    }

    // ---- deferred x-update: alpha_{t-1} from h^t, x^t; write outputs[t-1].x ----
    if (t > 0) {
      const float ab0 = cab[0], ab1 = cab[1], wb0 = cab[2], wb1 = cab[3];
      #pragma unroll
      for (int r = 0; r < 4; ++r) {
        const float aa0 = sigm(alv[0][r] + ab0), aa1 = sigm(alv[1][r] + ab1);
        const float X1 = x1[r], X2 = x2[r];
        const float dx1 = X2;
        const float dx2 = (-1.f - 2.f * X1 * X2) * X1 + (1.f - X1 * X1) * X2 + up0[r];
        const float xm1 = X1 + tpr[r] * dx1, xm2 = X2 + tpr[r] * dx2;
        const float xn1 = (1.f - aa0) * xm1 + aa0 * (wxv[0][r] + wb0);
        const float xn2 = (1.f - aa1) * xm2 + aa1 * (wxv[1][r] + wb1);
        x1[r] = xn1; x2[r] = xn2;
        if (hb == 0 && w == 0 && (l >> 3) == 0) {
          const int row = row0 + r;
          f2 xv = {xn1, xn2};
          f2 av = {aa0, aa1};
          __builtin_nontemporal_store(xv, (f2*)(out + OUT0 + (size_t)row * 262656 + (size_t)(t - 1) * 1026));
          __builtin_nontemporal_store(av, (f2*)(out + OUT3 + (size_t)row * 512 + (t - 1) * 2));
        }
      }
    }
    if (bid == 0 && tid == 0) {  // mats[t] from x^t (batch row 0)
      f4 mv = {0.f, 1.f, -1.f - 2.f * x1[0] * x2[0], 1.f - x1[0] * x1[0]};
      __builtin_nontemporal_store(mv, (f4*)(out + OUT4 + (size_t)t * 4));
    }

    // ---- gates: add x/inp head + bias, nonlinearities, c/h update ----
    float hcoef[4][5];
    #pragma unroll
    for (int g = 0; g < 4; ++g) {
      const int c5 = (g * 32 + jl) * 5;
      #pragma unroll
      for (int z = 0; z < 5; ++z) hcoef[g][z] = chead[c5 + z];
    }
    #pragma unroll
    for (int r = 0; r < 4; ++r) {
      float gvals[4] = {gva[0][r], gva[1][r], gvb[0][r], gvb[1][r]};
      #pragma unroll
      for (int g = 0; g < 4; ++g)
        gvals[g] += x1[r] * hcoef[g][0] + x2[r] * hcoef[g][1]
                  + uvr[r][0] * hcoef[g][2] + uvr[r][1] * hcoef[g][3] + hcoef[g][4];
      const float iv = sigm(gvals[0]), fv = sigm(gvals[1]);
      const float gg = tanh_f(gvals[2]), ov = sigm(gvals[3]);
      const float cn = fv * cst[r] + iv * gg;
      const float hn = ov * tanh_f(cn);
      cst[r] = cn;
      const int row = row0 + r;
      __bf16 hbv = (__bf16)hn;
      __hip_atomic_store((unsigned short*)(hw + (size_t)row * 1024 + gd),
                         __builtin_bit_cast(unsigned short, hbv),
                         __ATOMIC_RELAXED, __HIP_MEMORY_SCOPE_AGENT);
      __builtin_nontemporal_store(hn, out + OUT0 + (size_t)row * 262656 + (size_t)t * 1026 + 2 + gd);
      if (t == 255) {
        __builtin_nontemporal_store(hn, out + OUT1 + (size_t)row * 1026 + 2 + gd);
        __builtin_nontemporal_store(cn, out + OUT2 + (size_t)row * 1026 + 2 + gd);
      }
      up0[r] = uvr[r][0];
    }
    if (t == 255 && w == 0 && (l >> 3) == 0) {  // publish x^255 for final pass
      #pragma unroll
      for (int r = 0; r < 4; ++r) {
        xsh[(mq * 4 + r) * 2 + 0] = x1[r];
        xsh[(mq * 4 + r) * 2 + 1] = x2[r];
      }
    }

    mbar(bar, Mg, 32u * (uint32_t)(t + 2), tid);
  }

  // ---- final pass: alpha_255 / x^256 from h^256 (VALU dots; hb==0 blocks only) ----
  if (hb == 0 && tid < 32) {
    const int m = tid, row = Mg * 32 + m;
    const __bf16* hp = hbuf + (size_t)row * 1024;  // h^256 lives in buf0
    float s0 = 0.f, s1 = 0.f, s2 = 0.f, s3 = 0.f;
    #pragma unroll 2
    for (int k = 0; k < 1024; k += 8) {
      bf8 hv = ld_h(hp + k);
      #pragma unroll
      for (int j = 0; j < 8; ++j) {
        const float hf = (float)hv[j];
        s0 += hf * aw[k + j];        s1 += hf * aw[1024 + k + j];
        s2 += hf * wxw[k + j];       s3 += hf * wxw[1024 + k + j];
      }
    }
    const float aa0 = sigm(s0 + cab[0]), aa1 = sigm(s1 + cab[1]);
    const float X1 = xsh[m * 2], X2 = xsh[m * 2 + 1];
    const float u0 = inp[(size_t)row * 512 + 510];
    const float tp = tau[(size_t)row * 256 + 255];
    const float dx1 = X2;
    const float dx2 = (-1.f - 2.f * X1 * X2) * X1 + (1.f - X1 * X1) * X2 + u0;
    const float xm1 = X1 + tp * dx1, xm2 = X2 + tp * dx2;
    const float xn1 = (1.f - aa0) * xm1 + aa0 * (s2 + cab[2]);
    const float xn2 = (1.f - aa1) * xm2 + aa1 * (s3 + cab[3]);
    f2 xv = {xn1, xn2};
    f2 av = {aa0, aa1};
    __builtin_nontemporal_store(xv, (f2*)(out + OUT0 + (size_t)row * 262656 + (size_t)255 * 1026));
    __builtin_nontemporal_store(av, (f2*)(out + OUT3 + (size_t)row * 512 + 510));
    __builtin_nontemporal_store(xv, (f2*)(out + OUT1 + (size_t)row * 1026));
  }
}

extern "C" void kernel_launch(void* const* d_in, const int* in_sizes, int n_in,
                              void* d_out, int out_size, void* d_ws, size_t ws_size,
                              hipStream_t stream) {
  (void)in_sizes; (void)n_in; (void)out_size; (void)ws_size;
  uint32_t* bar = (uint32_t*)d_ws;
  __bf16* hbuf = (__bf16*)((char*)d_ws + 4096);  // 2 x 256 x 1024 bf16 = 1 MB

  ws_init<<<dim3(1), dim3(256), 0, stream>>>(bar);
  lstm_persist<<<dim3(256), dim3(256), 0, stream>>>(
      (const float*)d_in[0], (const float*)d_in[1], (const float*)d_in[2],
      (const float*)d_in[3], (const float*)d_in[4], (const float*)d_in[5],
      (const float*)d_in[6], (const float*)d_in[7], (const float*)d_in[8],
      (const float*)d_in[9], (float*)d_out, bar, hbuf);
}